// Round 1
// baseline (92391.852 us; speedup 1.0000x reference)
//
#include <hip/hip_runtime.h>

#define Bb 64
#define Tt 512
#define Dd 512
#define Hh 1024
#define OUT2_OFF 33554432  // 1024 * 32768

__global__ __launch_bounds__(256) void init_state_k(const float* __restrict__ state,
                                                    float* __restrict__ Hbuf) {
    int i = blockIdx.x * 256 + threadIdx.x;
    if (i < Bb * Hh) Hbuf[i] = state[i];
}

// Phase A (step t): Z = sigmoid(x_z + H@W_hz), R = sigmoid(x_r + H@W_hr); emit Z and R*H.
// grid.x = 512, block = (64, 4). Lane = batch b; (blockIdx.x*4+ty) = gate-column 0..2047.
__global__ __launch_bounds__(256) void gru_phaseA(
    const float* __restrict__ inp, const float* __restrict__ Hbuf,
    const float* __restrict__ Wxz, const float* __restrict__ Whz, const float* __restrict__ bz,
    const float* __restrict__ Wxr, const float* __restrict__ Whr, const float* __restrict__ br,
    float* __restrict__ Zbuf, float* __restrict__ RH, int t)
{
    const int b = threadIdx.x;
    int ncol = __builtin_amdgcn_readfirstlane(blockIdx.x * 4 + threadIdx.y); // wave-uniform
    const int gate = ncol >> 10;   // 0 = z, 1 = r
    const int n = ncol & 1023;

    const float* __restrict__ Wx = gate ? Wxr : Wxz;
    const float* __restrict__ Wh = gate ? Whr : Whz;
    float acc = gate ? br[n] : bz[n];

    const float* __restrict__ arow = inp + ((size_t)(b * Tt + t)) * Dd;
    #pragma unroll 4
    for (int d = 0; d < Dd; d += 4) {
        float4 a = *reinterpret_cast<const float4*>(arow + d);
        acc += a.x * Wx[(d + 0) * Hh + n];
        acc += a.y * Wx[(d + 1) * Hh + n];
        acc += a.z * Wx[(d + 2) * Hh + n];
        acc += a.w * Wx[(d + 3) * Hh + n];
    }
    const float* __restrict__ hrow = Hbuf + b * Hh;
    #pragma unroll 4
    for (int k = 0; k < Hh; k += 4) {
        float4 h = *reinterpret_cast<const float4*>(hrow + k);
        acc += h.x * Wh[(k + 0) * Hh + n];
        acc += h.y * Wh[(k + 1) * Hh + n];
        acc += h.z * Wh[(k + 2) * Hh + n];
        acc += h.w * Wh[(k + 3) * Hh + n];
    }
    const float g = 1.0f / (1.0f + __expf(-acc));
    if (gate == 0) Zbuf[b * Hh + n] = g;
    else           RH[b * Hh + n] = g * Hbuf[b * Hh + n];
}

// Phase B (step t): H~ = tanh(x_h + (R*H)@W_hh); Hn = Z*H + (1-Z)*H~; write out + update H.
// grid.x = 256, block = (64, 4).
__global__ __launch_bounds__(256) void gru_phaseB(
    const float* __restrict__ inp, float* __restrict__ Hbuf,
    const float* __restrict__ Wxh, const float* __restrict__ Whh, const float* __restrict__ bh,
    const float* __restrict__ Zbuf, const float* __restrict__ RH,
    float* __restrict__ out, int t)
{
    const int b = threadIdx.x;
    const int n = __builtin_amdgcn_readfirstlane(blockIdx.x * 4 + threadIdx.y);

    float acc = bh[n];
    const float* __restrict__ arow = inp + ((size_t)(b * Tt + t)) * Dd;
    #pragma unroll 4
    for (int d = 0; d < Dd; d += 4) {
        float4 a = *reinterpret_cast<const float4*>(arow + d);
        acc += a.x * Wxh[(d + 0) * Hh + n];
        acc += a.y * Wxh[(d + 1) * Hh + n];
        acc += a.z * Wxh[(d + 2) * Hh + n];
        acc += a.w * Wxh[(d + 3) * Hh + n];
    }
    const float* __restrict__ rrow = RH + b * Hh;
    #pragma unroll 4
    for (int k = 0; k < Hh; k += 4) {
        float4 r = *reinterpret_cast<const float4*>(rrow + k);
        acc += r.x * Whh[(k + 0) * Hh + n];
        acc += r.y * Whh[(k + 1) * Hh + n];
        acc += r.z * Whh[(k + 2) * Hh + n];
        acc += r.w * Whh[(k + 3) * Hh + n];
    }
    const float ht   = tanhf(acc);
    const float z    = Zbuf[b * Hh + n];
    const float hold = Hbuf[b * Hh + n];
    const float hn   = z * hold + (1.0f - z) * ht;

    Hbuf[b * Hh + n] = hn;                                   // in-place: 1 reader/writer per (b,n)
    out[(size_t)n * (Tt * Bb) + (size_t)t * Bb + b] = hn;    // outputs[h, t*B+b]
    if (t == Tt - 1) out[(size_t)OUT2_OFF + (size_t)b * Hh + n] = hn;  // H_final[b,h]
}

extern "C" void kernel_launch(void* const* d_in, const int* in_sizes, int n_in,
                              void* d_out, int out_size, void* d_ws, size_t ws_size,
                              hipStream_t stream) {
    const float* inp   = (const float*)d_in[0];
    const float* state = (const float*)d_in[1];
    const float* Wxz   = (const float*)d_in[2];
    const float* Whz   = (const float*)d_in[3];
    const float* bz    = (const float*)d_in[4];
    const float* Wxr   = (const float*)d_in[5];
    const float* Whr   = (const float*)d_in[6];
    const float* br    = (const float*)d_in[7];
    const float* Wxh   = (const float*)d_in[8];
    const float* Whh   = (const float*)d_in[9];
    const float* bh    = (const float*)d_in[10];
    float* out = (float*)d_out;

    float* ws   = (float*)d_ws;
    float* Hbuf = ws;               // 64*1024
    float* Zbuf = ws + 65536;       // 64*1024
    float* RH   = ws + 131072;      // 64*1024

    init_state_k<<<dim3(256), dim3(256), 0, stream>>>(state, Hbuf);

    for (int t = 0; t < Tt; ++t) {
        gru_phaseA<<<dim3(512), dim3(64, 4), 0, stream>>>(
            inp, Hbuf, Wxz, Whz, bz, Wxr, Whr, br, Zbuf, RH, t);
        gru_phaseB<<<dim3(256), dim3(64, 4), 0, stream>>>(
            inp, Hbuf, Wxh, Whh, bh, Zbuf, RH, out, t);
    }
}

// Round 2
// 21734.300 us; speedup vs baseline: 4.2510x; 4.2510x over previous
//
#include <hip/hip_runtime.h>
#include <hip/hip_bf16.h>

typedef unsigned short ushort_t;
typedef unsigned int uint32;
typedef short bf16x8 __attribute__((ext_vector_type(8)));
typedef float f32x4 __attribute__((ext_vector_type(4)));

#define Bb 64
#define Tt 512
#define Dd 512
#define Hh 1024
#define KK 1536
#define NBLK 64
#define OUT2_OFF 33554432ull

// ws layout (bytes):
//   HB  [64][1024] bf16   @ 0         (131072)
//   RH  [64][1024] bf16   @ 131072    (131072)
//   WT  [3][1024][1536] bf16 @ 262144 (9437184)   g: 0=z 1=r 2=h, [n][k], k = [x 0..511 | h 512..1535]
//   bar 2 x uint32        @ 9699328

__device__ inline ushort_t f2b(float f) {
    __hip_bfloat16 h = __float2bfloat16(f);
    return __builtin_bit_cast(ushort_t, h);
}
__device__ inline float b2f(ushort_t u) {
    uint32 x = ((uint32)u) << 16;
    return __builtin_bit_cast(float, x);
}

__device__ inline bf16x8 ld_bf8(const ushort_t* p) {
    uint4 v = *reinterpret_cast<const uint4*>(p);
    return __builtin_bit_cast(bf16x8, v);
}
__device__ inline bf16x8 ld_x8(const float* p) {
    float4 u = *reinterpret_cast<const float4*>(p);
    float4 v = *reinterpret_cast<const float4*>(p + 4);
    bf16x8 a;
    a[0] = (short)f2b(u.x); a[1] = (short)f2b(u.y); a[2] = (short)f2b(u.z); a[3] = (short)f2b(u.w);
    a[4] = (short)f2b(v.x); a[5] = (short)f2b(v.y); a[6] = (short)f2b(v.z); a[7] = (short)f2b(v.w);
    return a;
}

#define MFMA(a, b, c) __builtin_amdgcn_mfma_f32_16x16x32_bf16((a), (b), (c), 0, 0, 0)

__device__ inline void grid_barrier(uint32* cnt, uint32* gen, unsigned nb) {
    __syncthreads();
    if (threadIdx.x == 0) {
        __threadfence();  // release: publish this block's global writes
        uint32 g = __hip_atomic_load(gen, __ATOMIC_RELAXED, __HIP_MEMORY_SCOPE_AGENT);
        uint32 a = __hip_atomic_fetch_add(cnt, 1u, __ATOMIC_RELAXED, __HIP_MEMORY_SCOPE_AGENT);
        if (a == nb - 1) {
            __hip_atomic_store(cnt, 0u, __ATOMIC_RELAXED, __HIP_MEMORY_SCOPE_AGENT);
            __hip_atomic_fetch_add(gen, 1u, __ATOMIC_RELEASE, __HIP_MEMORY_SCOPE_AGENT);
        } else {
            while (__hip_atomic_load(gen, __ATOMIC_RELAXED, __HIP_MEMORY_SCOPE_AGENT) == g) {
                __builtin_amdgcn_s_sleep(2);
            }
        }
        __threadfence();  // acquire: invalidate L1/L2 so fresh HB/RH are visible
    }
    __syncthreads();
}

__global__ __launch_bounds__(256) void k_init(const float* __restrict__ state,
                                              ushort_t* __restrict__ HB, uint32* bar) {
    int i = blockIdx.x * 256 + threadIdx.x;
    if (i < Bb * Hh) HB[i] = f2b(state[i]);
    if (i < 2) bar[i] = 0;
}

// WT[g][n][k] = bf16( k<512 ? Wx_g[k][n] : Wh_g[k-512][n] ), LDS-tiled 64x64 transpose.
__global__ __launch_bounds__(256) void k_wt(const float* __restrict__ Wxz, const float* __restrict__ Whz,
                                            const float* __restrict__ Wxr, const float* __restrict__ Whr,
                                            const float* __restrict__ Wxh, const float* __restrict__ Whh,
                                            ushort_t* __restrict__ WT) {
    __shared__ float lds[64][65];
    int id = blockIdx.x;
    int g = id / 384, rem = id % 384, nt = rem / 24, kt = rem % 24;
    const float* Wx = (g == 0) ? Wxz : (g == 1) ? Wxr : Wxh;
    const float* Wh = (g == 0) ? Whz : (g == 1) ? Whr : Whh;
    int n0 = nt * 64, k0 = kt * 64;
    int tr = threadIdx.x >> 6, tc = threadIdx.x & 63;
    #pragma unroll
    for (int i = 0; i < 16; i++) {
        int kl = i * 4 + tr;
        int k = k0 + kl;
        float v = (k < 512) ? Wx[(size_t)k * Hh + n0 + tc] : Wh[(size_t)(k - 512) * Hh + n0 + tc];
        lds[kl][tc] = v;
    }
    __syncthreads();
    #pragma unroll
    for (int i = 0; i < 16; i++) {
        int nl = i * 4 + tr;
        WT[((size_t)g * Hh + n0 + nl) * KK + k0 + tc] = f2b(lds[tc][nl]);
    }
}

__global__ __launch_bounds__(256) void gru_persist(
    const float* __restrict__ inp,
    const float* __restrict__ bz, const float* __restrict__ br, const float* __restrict__ bh,
    ushort_t* HB, ushort_t* RH, const ushort_t* __restrict__ WT,
    uint32* bar, float* __restrict__ out) {
    __shared__ float Zs[Bb * 16];

    const int bi = blockIdx.x;
    const int tid = threadIdx.x;
    const int l = tid & 63, w = tid >> 6;
    const int lrow = l & 15;          // A-frag row within m-tile / B-frag col within n-tile
    const int lk8 = (l >> 4) << 3;    // k sub-block offset (0,8,16,24)

    const int arow = w * 16 + lrow;                                   // batch row for frag loads
    const float*    xbase = inp + (size_t)arow * (Tt * Dd) + lk8;     // + t*Dd + kk*32
    const ushort_t* hbase = HB + arow * Hh + lk8;
    const ushort_t* rbase = RH + arow * Hh + lk8;
    const int ncol = bi * 16 + lrow;                                  // global output column
    const ushort_t* wzb = WT + (size_t)(0 * Hh + ncol) * KK + lk8;
    const ushort_t* wrb = WT + (size_t)(1 * Hh + ncol) * KK + lk8;
    const ushort_t* whb = WT + (size_t)(2 * Hh + ncol) * KK + lk8;
    const float bzv = bz[ncol], brv = br[ncol], bhv = bh[ncol];

    for (int t = 0; t < Tt; ++t) {
        const float* xp = xbase + t * Dd;

        // ================= phase A: Z, R =================
        f32x4 az0 = {0,0,0,0}, az1 = {0,0,0,0}, ar0 = {0,0,0,0}, ar1 = {0,0,0,0};
        #pragma unroll
        for (int kk = 0; kk < 16; kk += 2) {          // x part (k 0..511)
            bf16x8 a0 = ld_x8(xp + kk * 32);
            bf16x8 a1 = ld_x8(xp + kk * 32 + 32);
            bf16x8 b0 = ld_bf8(wzb + kk * 32),       b1 = ld_bf8(wzb + kk * 32 + 32);
            bf16x8 c0 = ld_bf8(wrb + kk * 32),       c1 = ld_bf8(wrb + kk * 32 + 32);
            az0 = MFMA(a0, b0, az0); az1 = MFMA(a1, b1, az1);
            ar0 = MFMA(a0, c0, ar0); ar1 = MFMA(a1, c1, ar1);
        }
        #pragma unroll
        for (int kk = 0; kk < 32; kk += 2) {          // h part (k 512..1535)
            bf16x8 a0 = ld_bf8(hbase + kk * 32);
            bf16x8 a1 = ld_bf8(hbase + kk * 32 + 32);
            bf16x8 b0 = ld_bf8(wzb + 512 + kk * 32), b1 = ld_bf8(wzb + 512 + kk * 32 + 32);
            bf16x8 c0 = ld_bf8(wrb + 512 + kk * 32), c1 = ld_bf8(wrb + 512 + kk * 32 + 32);
            az0 = MFMA(a0, b0, az0); az1 = MFMA(a1, b1, az1);
            ar0 = MFMA(a0, c0, ar0); ar1 = MFMA(a1, c1, ar1);
        }
        f32x4 az = az0 + az1, ar = ar0 + ar1;
        #pragma unroll
        for (int j = 0; j < 4; j++) {
            int brow = w * 16 + ((l >> 4) << 2) + j;  // D row = batch
            float z = 1.f / (1.f + __expf(-(az[j] + bzv)));
            float r = 1.f / (1.f + __expf(-(ar[j] + brv)));
            float hold = b2f(HB[brow * Hh + ncol]);
            RH[brow * Hh + ncol] = f2b(r * hold);
            Zs[brow * 16 + lrow] = z;
        }
        grid_barrier(bar, bar + 1, NBLK);

        // ================= phase B: H~, blend =================
        f32x4 ah0 = {0,0,0,0}, ah1 = {0,0,0,0};
        #pragma unroll
        for (int kk = 0; kk < 16; kk += 2) {          // x part
            bf16x8 a0 = ld_x8(xp + kk * 32);
            bf16x8 a1 = ld_x8(xp + kk * 32 + 32);
            bf16x8 b0 = ld_bf8(whb + kk * 32), b1 = ld_bf8(whb + kk * 32 + 32);
            ah0 = MFMA(a0, b0, ah0); ah1 = MFMA(a1, b1, ah1);
        }
        #pragma unroll
        for (int kk = 0; kk < 32; kk += 2) {          // (R*H) part
            bf16x8 a0 = ld_bf8(rbase + kk * 32);
            bf16x8 a1 = ld_bf8(rbase + kk * 32 + 32);
            bf16x8 b0 = ld_bf8(whb + 512 + kk * 32), b1 = ld_bf8(whb + 512 + kk * 32 + 32);
            ah0 = MFMA(a0, b0, ah0); ah1 = MFMA(a1, b1, ah1);
        }
        f32x4 ah = ah0 + ah1;
        #pragma unroll
        for (int j = 0; j < 4; j++) {
            int brow = w * 16 + ((l >> 4) << 2) + j;
            float pre = ah[j] + bhv;
            float e = __expf(-2.f * fabsf(pre));
            float th = (1.f - e) / (1.f + e);
            th = copysignf(th, pre);
            float z = Zs[brow * 16 + lrow];
            float hold = b2f(HB[brow * Hh + ncol]);
            float hn = z * hold + (1.f - z) * th;
            HB[brow * Hh + ncol] = f2b(hn);
            out[(size_t)ncol * (Tt * Bb) + (size_t)t * Bb + brow] = hn;
            if (t == Tt - 1) out[OUT2_OFF + (size_t)brow * Hh + ncol] = hn;
        }
        grid_barrier(bar, bar + 1, NBLK);
    }
}

extern "C" void kernel_launch(void* const* d_in, const int* in_sizes, int n_in,
                              void* d_out, int out_size, void* d_ws, size_t ws_size,
                              hipStream_t stream) {
    const float* inp   = (const float*)d_in[0];
    const float* state = (const float*)d_in[1];
    const float* Wxz   = (const float*)d_in[2];
    const float* Whz   = (const float*)d_in[3];
    const float* bz    = (const float*)d_in[4];
    const float* Wxr   = (const float*)d_in[5];
    const float* Whr   = (const float*)d_in[6];
    const float* br    = (const float*)d_in[7];
    const float* Wxh   = (const float*)d_in[8];
    const float* Whh   = (const float*)d_in[9];
    const float* bh    = (const float*)d_in[10];
    float* out = (float*)d_out;

    char* ws = (char*)d_ws;
    ushort_t* HB  = (ushort_t*)(ws);
    ushort_t* RH  = (ushort_t*)(ws + 131072);
    ushort_t* WT  = (ushort_t*)(ws + 262144);
    uint32*   bar = (uint32*)(ws + 9699328);

    k_init<<<dim3(256), dim3(256), 0, stream>>>(state, HB, bar);
    k_wt<<<dim3(1152), dim3(256), 0, stream>>>(Wxz, Whz, Wxr, Whr, Wxh, Whh, WT);

    void* args[] = {(void*)&inp, (void*)&bz, (void*)&br, (void*)&bh,
                    (void*)&HB, (void*)&RH, (void*)&WT, (void*)&bar, (void*)&out};
    hipError_t e = hipLaunchCooperativeKernel((const void*)gru_persist, dim3(NBLK), dim3(256),
                                              args, 0, stream);
    if (e != hipSuccess) {
        // 64 tiny blocks on 256 CUs are always co-resident; custom barrier keeps this correct.
        gru_persist<<<dim3(NBLK), dim3(256), 0, stream>>>(inp, bz, br, bh, HB, RH, WT, bar, out);
    }
}

// Round 3
// 11939.450 us; speedup vs baseline: 7.7384x; 1.8204x over previous
//
#include <hip/hip_runtime.h>
#include <hip/hip_bf16.h>

typedef unsigned short ushort_t;
typedef unsigned int uint32;
typedef short bf16x8 __attribute__((ext_vector_type(8)));
typedef float f32x4 __attribute__((ext_vector_type(4)));

#define Bb 64
#define Tt 512
#define Dd 512
#define Hh 1024
#define KK 1536
#define KP 1544   // padded LDS row stride (elements): breaks power-of-2 bank aliasing
#define NBLK 64
#define OUT2_OFF 33554432ull

// ws layout (bytes):
//   HB    [64][1024] bf16      @ 0        (131072)
//   RH    [64][1024] bf16      @ 131072   (131072)
//   WT    [3][1024][1536] bf16 @ 262144   (9437184)   [g][n][k], k = [x 0..511 | h 512..1535]
//   flags 64 x 128B + gen      @ 9699328  (~8.5 KB)

__device__ inline ushort_t f2b(float f) {
    __hip_bfloat16 h = __float2bfloat16(f);
    return __builtin_bit_cast(ushort_t, h);
}
__device__ inline float b2f(ushort_t u) {
    uint32 x = ((uint32)u) << 16;
    return __builtin_bit_cast(float, x);
}
__device__ inline bf16x8 ld_bf8(const ushort_t* p) {       // global or LDS, 16B
    uint4 v = *reinterpret_cast<const uint4*>(p);
    return __builtin_bit_cast(bf16x8, v);
}
__device__ inline bf16x8 ld_x8(const float* p) {           // 8 f32 -> 8 bf16 (RNE)
    float4 u = *reinterpret_cast<const float4*>(p);
    float4 v = *reinterpret_cast<const float4*>(p + 4);
    bf16x8 a;
    a[0] = (short)f2b(u.x); a[1] = (short)f2b(u.y); a[2] = (short)f2b(u.z); a[3] = (short)f2b(u.w);
    a[4] = (short)f2b(v.x); a[5] = (short)f2b(v.y); a[6] = (short)f2b(v.z); a[7] = (short)f2b(v.w);
    return a;
}

#define MFMA(a, b, c) __builtin_amdgcn_mfma_f32_16x16x32_bf16((a), (b), (c), 0, 0, 0)

// Parallel-arrival grid barrier. Monotonic val, no resets, no atomic RMW.
// Block bi's lane0 stores flags[bi*32]=val (release). Block 0's wave0 gathers all 64
// flags (one 64-lane load per poll) until __all(>= val), then publishes gen=val.
// Other blocks spin on the single gen line.
__device__ inline void flag_barrier(uint32* flags, uint32 val) {
    __syncthreads();
    if (threadIdx.x < 64) {
        uint32* gen = flags + 2048;
        if (threadIdx.x == 0) {
            __threadfence();
            __hip_atomic_store(flags + (uint32)blockIdx.x * 32, val,
                               __ATOMIC_RELEASE, __HIP_MEMORY_SCOPE_AGENT);
        }
        if (blockIdx.x == 0) {
            uint32 v;
            do {
                v = __hip_atomic_load(flags + threadIdx.x * 32,
                                      __ATOMIC_RELAXED, __HIP_MEMORY_SCOPE_AGENT);
            } while (!__all((int)(v >= val)));
            __threadfence();
            if (threadIdx.x == 0)
                __hip_atomic_store(gen, val, __ATOMIC_RELEASE, __HIP_MEMORY_SCOPE_AGENT);
        } else if (threadIdx.x == 0) {
            while (__hip_atomic_load(gen, __ATOMIC_RELAXED, __HIP_MEMORY_SCOPE_AGENT) < val) {}
            __threadfence();
        }
    }
    __syncthreads();
}

__global__ __launch_bounds__(256) void k_init(const float* __restrict__ state,
                                              ushort_t* __restrict__ HB, uint32* flags) {
    int i = blockIdx.x * 256 + threadIdx.x;
    if (i < Bb * Hh) HB[i] = f2b(state[i]);
    if (i < 2112) flags[i] = 0;
}

// WT[g][n][k] = bf16( k<512 ? Wx_g[k][n] : Wh_g[k-512][n] ), LDS-tiled 64x64 transpose.
__global__ __launch_bounds__(256) void k_wt(const float* __restrict__ Wxz, const float* __restrict__ Whz,
                                            const float* __restrict__ Wxr, const float* __restrict__ Whr,
                                            const float* __restrict__ Wxh, const float* __restrict__ Whh,
                                            ushort_t* __restrict__ WT) {
    __shared__ float lds[64][65];
    int id = blockIdx.x;
    int g = id / 384, rem = id % 384, nt = rem / 24, kt = rem % 24;
    const float* Wx = (g == 0) ? Wxz : (g == 1) ? Wxr : Wxh;
    const float* Wh = (g == 0) ? Whz : (g == 1) ? Whr : Whh;
    int n0 = nt * 64, k0 = kt * 64;
    int tr = threadIdx.x >> 6, tc = threadIdx.x & 63;
    #pragma unroll
    for (int i = 0; i < 16; i++) {
        int kl = i * 4 + tr;
        int k = k0 + kl;
        float v = (k < 512) ? Wx[(size_t)k * Hh + n0 + tc] : Wh[(size_t)(k - 512) * Hh + n0 + tc];
        lds[kl][tc] = v;
    }
    __syncthreads();
    #pragma unroll
    for (int i = 0; i < 16; i++) {
        int nl = i * 4 + tr;
        WT[((size_t)g * Hh + n0 + nl) * KK + k0 + tc] = f2b(lds[tc][nl]);
    }
}

__global__ __launch_bounds__(256) void gru_persist(
    const float* __restrict__ inp,
    const float* __restrict__ bz, const float* __restrict__ br, const float* __restrict__ bh,
    ushort_t* HB, ushort_t* RH, const ushort_t* __restrict__ WT,
    uint32* flags, float* __restrict__ out) {
    __shared__ ushort_t WL[3 * 16 * KP];   // 148224 B — weights resident across all 512 steps

    const int bi = blockIdx.x;
    const int tid = threadIdx.x;

    // ---- prologue: stage this block's [3][16][1536] weight slice into padded LDS ----
    for (int r = tid >> 4; r < 48; r += 16) {              // r = g*16 + nl
        const ushort_t* src = WT + ((size_t)(r >> 4) * Hh + bi * 16 + (r & 15)) * KK;
        ushort_t* dst = WL + (size_t)r * KP;
        for (int c = tid & 15; c < 192; c += 16) {         // 192 x 16B = 3072B per row
            uint4 v = *reinterpret_cast<const uint4*>(src + c * 8);
            *reinterpret_cast<uint4*>(dst + c * 8) = v;
        }
    }

    const int l = tid & 63, w = tid >> 6;
    const int lrow = l & 15, lq = l >> 4;
    const int lk8 = lq << 3;

    const int arow = w * 16 + lrow;                        // A-frag row (batch)
    const int brow0 = w * 16 + lq * 4;                     // C/D frag row base (batch)
    const float*    xbase = inp + (size_t)arow * (Tt * Dd) + lk8;
    const ushort_t* hbase = HB + arow * Hh + lk8;
    const ushort_t* rbase = RH + arow * Hh + lk8;
    const int ncol = bi * 16 + lrow;
    const ushort_t* wlz = WL + (0 * 16 + lrow) * KP + lk8;
    const ushort_t* wlr = WL + (1 * 16 + lrow) * KP + lk8;
    const ushort_t* wlh = WL + (2 * 16 + lrow) * KP + lk8;
    const float bzv = bz[ncol], brv = br[ncol], bhv = bh[ncol];

    float hold[4], zreg[4];
    #pragma unroll
    for (int j = 0; j < 4; j++) hold[j] = b2f(HB[(size_t)(brow0 + j) * Hh + ncol]);

    __syncthreads();

    for (int t = 0; t < Tt; ++t) {
        const float* xp = xbase + t * Dd;

        // ---- x fragments for this step: loaded once, feed all 3 gates ----
        bf16x8 xa[16];
        #pragma unroll
        for (int i = 0; i < 16; i++) xa[i] = ld_x8(xp + i * 32);

        f32x4 az0 = {0,0,0,0}, az1 = {0,0,0,0}, ar0 = {0,0,0,0}, ar1 = {0,0,0,0};
        f32x4 ah0 = {0,0,0,0}, ah1 = {0,0,0,0}, ah2 = {0,0,0,0}, ah3 = {0,0,0,0};

        // ---- phase A: x-part of z, r, AND h (h's x-part has no dependence on R) ----
        #pragma unroll
        for (int kk = 0; kk < 16; kk += 2) {
            const int o = kk * 32;
            az0 = MFMA(xa[kk],     ld_bf8(wlz + o),      az0);
            az1 = MFMA(xa[kk + 1], ld_bf8(wlz + o + 32), az1);
            ar0 = MFMA(xa[kk],     ld_bf8(wlr + o),      ar0);
            ar1 = MFMA(xa[kk + 1], ld_bf8(wlr + o + 32), ar1);
            ah0 = MFMA(xa[kk],     ld_bf8(wlh + o),      ah0);
            ah1 = MFMA(xa[kk + 1], ld_bf8(wlh + o + 32), ah1);
        }
        // ---- phase A: h-part of z, r (K = 1024 over H) ----
        #pragma unroll
        for (int kk = 0; kk < 32; kk += 2) {
            const int o = kk * 32;
            bf16x8 a0 = ld_bf8(hbase + o);
            bf16x8 a1 = ld_bf8(hbase + o + 32);
            az0 = MFMA(a0, ld_bf8(wlz + 512 + o),      az0);
            az1 = MFMA(a1, ld_bf8(wlz + 512 + o + 32), az1);
            ar0 = MFMA(a0, ld_bf8(wlr + 512 + o),      ar0);
            ar1 = MFMA(a1, ld_bf8(wlr + 512 + o + 32), ar1);
        }
        f32x4 az = az0 + az1, ar = ar0 + ar1;
        #pragma unroll
        for (int j = 0; j < 4; j++) {
            float z = 1.f / (1.f + __expf(-(az[j] + bzv)));
            float r = 1.f / (1.f + __expf(-(ar[j] + brv)));
            zreg[j] = z;
            RH[(size_t)(brow0 + j) * Hh + ncol] = f2b(r * hold[j]);
        }
        flag_barrier(flags, 2u * (uint32)t + 1u);

        // ---- phase B: h-part of h-gate (K = 1024 over R*H), 4 independent chains ----
        #pragma unroll
        for (int kk = 0; kk < 32; kk += 4) {
            const int o = kk * 32;
            bf16x8 a0 = ld_bf8(rbase + o);
            bf16x8 a1 = ld_bf8(rbase + o + 32);
            bf16x8 a2 = ld_bf8(rbase + o + 64);
            bf16x8 a3 = ld_bf8(rbase + o + 96);
            ah0 = MFMA(a0, ld_bf8(wlh + 512 + o),      ah0);
            ah1 = MFMA(a1, ld_bf8(wlh + 512 + o + 32), ah1);
            ah2 = MFMA(a2, ld_bf8(wlh + 512 + o + 64), ah2);
            ah3 = MFMA(a3, ld_bf8(wlh + 512 + o + 96), ah3);
        }
        f32x4 ah = (ah0 + ah1) + (ah2 + ah3);
        float hn[4];
        #pragma unroll
        for (int j = 0; j < 4; j++) {
            float pre = ah[j] + bhv;
            float e = __expf(-2.f * fabsf(pre));
            float th = (1.f - e) / (1.f + e);
            th = copysignf(th, pre);
            float v = zreg[j] * hold[j] + (1.f - zreg[j]) * th;
            hold[j] = v;
            hn[j] = v;
            HB[(size_t)(brow0 + j) * Hh + ncol] = f2b(v);
        }
        *reinterpret_cast<float4*>(out + (size_t)ncol * (Tt * Bb) + (size_t)t * Bb + brow0) =
            make_float4(hn[0], hn[1], hn[2], hn[3]);
        if (t == Tt - 1) {
            #pragma unroll
            for (int j = 0; j < 4; j++)
                out[OUT2_OFF + (size_t)(brow0 + j) * Hh + ncol] = hn[j];
        }
        flag_barrier(flags, 2u * (uint32)t + 2u);
    }
}

extern "C" void kernel_launch(void* const* d_in, const int* in_sizes, int n_in,
                              void* d_out, int out_size, void* d_ws, size_t ws_size,
                              hipStream_t stream) {
    const float* inp   = (const float*)d_in[0];
    const float* state = (const float*)d_in[1];
    const float* Wxz   = (const float*)d_in[2];
    const float* Whz   = (const float*)d_in[3];
    const float* bz    = (const float*)d_in[4];
    const float* Wxr   = (const float*)d_in[5];
    const float* Whr   = (const float*)d_in[6];
    const float* br    = (const float*)d_in[7];
    const float* Wxh   = (const float*)d_in[8];
    const float* Whh   = (const float*)d_in[9];
    const float* bh    = (const float*)d_in[10];
    float* out = (float*)d_out;

    char* ws = (char*)d_ws;
    ushort_t* HB    = (ushort_t*)(ws);
    ushort_t* RH    = (ushort_t*)(ws + 131072);
    ushort_t* WT    = (ushort_t*)(ws + 262144);
    uint32*   flags = (uint32*)(ws + 9699328);

    k_init<<<dim3(256), dim3(256), 0, stream>>>(state, HB, flags);
    k_wt<<<dim3(1152), dim3(256), 0, stream>>>(Wxz, Whz, Wxr, Whr, Wxh, Whh, WT);

    void* args[] = {(void*)&inp, (void*)&bz, (void*)&br, (void*)&bh,
                    (void*)&HB, (void*)&RH, (void*)&WT, (void*)&flags, (void*)&out};
    hipError_t e = hipLaunchCooperativeKernel((const void*)gru_persist, dim3(NBLK), dim3(256),
                                              args, 0, stream);
    if (e != hipSuccess) {
        // 64 blocks, 1 per CU (148KB LDS) on 256 CUs — always co-resident; flag barrier is safe.
        gru_persist<<<dim3(NBLK), dim3(256), 0, stream>>>(inp, bz, br, bh, HB, RH, WT, flags, out);
    }
}

// Round 4
// 9810.722 us; speedup vs baseline: 9.4174x; 1.2170x over previous
//
#include <hip/hip_runtime.h>
#include <hip/hip_bf16.h>

typedef unsigned short ushort_t;
typedef unsigned int uint32;
typedef unsigned long long ull;
typedef short bf16x8 __attribute__((ext_vector_type(8)));
typedef float f32x4 __attribute__((ext_vector_type(4)));

#define Bb 64
#define Tt 512
#define Dd 512
#define Hh 1024
#define KK 1536
#define KP 1544   // LDS row stride (elem); 2-way bank alias only (free per m136)
#define NBLK 64
#define OUT2_OFF 33554432ull
#define FLAGS_OFF 9699328ull
#define XB_OFF    9707776ull          // 16B aligned
#define XB_BYTES  33554432ull         // [64][512][512] bf16

// ws layout: HB @0 (128K) | RH @131072 (128K) | WT @262144 (9.4M) | flags @9699328 | XB @9707776 (32M, optional)

__device__ inline ushort_t f2b(float f) {
    __hip_bfloat16 h = __float2bfloat16(f);
    return __builtin_bit_cast(ushort_t, h);
}
__device__ inline float b2f(ushort_t u) {
    uint32 x = ((uint32)u) << 16;
    return __builtin_bit_cast(float, x);
}
__device__ inline bf16x8 ld_bf8(const ushort_t* p) {        // plain 16B (LDS or global)
    uint4 v = *reinterpret_cast<const uint4*>(p);
    return __builtin_bit_cast(bf16x8, v);
}
__device__ inline bf16x8 ld_x8(const float* p) {            // 8 f32 -> 8 bf16 (RNE)
    float4 u = *reinterpret_cast<const float4*>(p);
    float4 v = *reinterpret_cast<const float4*>(p + 4);
    bf16x8 a;
    a[0] = (short)f2b(u.x); a[1] = (short)f2b(u.y); a[2] = (short)f2b(u.z); a[3] = (short)f2b(u.w);
    a[4] = (short)f2b(v.x); a[5] = (short)f2b(v.y); a[6] = (short)f2b(v.z); a[7] = (short)f2b(v.w);
    return a;
}
// device-coherent (LLC) 16B load as 2x relaxed agent atomics — bypasses L1/L2, NO cache flush
__device__ inline bf16x8 ld_a8(const ushort_t* p) {
    union { ull q[2]; bf16x8 v; } u;
    u.q[0] = __hip_atomic_load((const ull*)p,       __ATOMIC_RELAXED, __HIP_MEMORY_SCOPE_AGENT);
    u.q[1] = __hip_atomic_load((const ull*)(p + 4), __ATOMIC_RELAXED, __HIP_MEMORY_SCOPE_AGENT);
    return u.v;
}
__device__ inline void st_a8(ushort_t* p, ull v) {
    __hip_atomic_store((ull*)p, v, __ATOMIC_RELAXED, __HIP_MEMORY_SCOPE_AGENT);
}

#define MFMA(a, b, c) __builtin_amdgcn_mfma_f32_16x16x32_bf16((a), (b), (c), 0, 0, 0)

// Split barrier. Data stores are device-scope atomics, so visibility needs only vmcnt drain —
// no buffer_wbl2 / buffer_inv ever executes in the main loop (L2 keeps x + out write-combining).
__device__ inline void b_arrive(uint32* flags, uint32 val) {
    asm volatile("s_waitcnt vmcnt(0)" ::: "memory");   // each wave drains its own sc1 stores
    __syncthreads();                                    // all 4 waves drained
    if (threadIdx.x == 0)
        __hip_atomic_store(flags + (uint32)blockIdx.x * 32, val,
                           __ATOMIC_RELAXED, __HIP_MEMORY_SCOPE_AGENT);
}
__device__ inline void b_wait(uint32* flags, uint32 val) {
    if (threadIdx.x < 64) {                             // wave 0 gathers all 64 flags per poll
        uint32 v;
        do {
            v = __hip_atomic_load(flags + threadIdx.x * 32,
                                  __ATOMIC_RELAXED, __HIP_MEMORY_SCOPE_AGENT);
        } while (__any((int)(v < val)));
    }
    __syncthreads();
    asm volatile("" ::: "memory");
}

__global__ __launch_bounds__(256) void k_init(const float* __restrict__ state,
                                              ushort_t* __restrict__ HB, uint32* flags) {
    int i = blockIdx.x * 256 + threadIdx.x;
    if (i < Bb * Hh) HB[i] = f2b(state[i]);
    if (i < 2112) flags[i] = 0;
}

__global__ __launch_bounds__(256) void k_xb(const float* __restrict__ inp,
                                            ushort_t* __restrict__ XB) {
    size_t i = ((size_t)blockIdx.x * 256 + threadIdx.x) * 8;
    bf16x8 v = ld_x8(inp + i);
    *reinterpret_cast<uint4*>(XB + i) = __builtin_bit_cast(uint4, v);
}

// WT[g][n][k] = bf16( k<512 ? Wx_g[k][n] : Wh_g[k-512][n] )
__global__ __launch_bounds__(256) void k_wt(const float* __restrict__ Wxz, const float* __restrict__ Whz,
                                            const float* __restrict__ Wxr, const float* __restrict__ Whr,
                                            const float* __restrict__ Wxh, const float* __restrict__ Whh,
                                            ushort_t* __restrict__ WT) {
    __shared__ float lds[64][65];
    int id = blockIdx.x;
    int g = id / 384, rem = id % 384, nt = rem / 24, kt = rem % 24;
    const float* Wx = (g == 0) ? Wxz : (g == 1) ? Wxr : Wxh;
    const float* Wh = (g == 0) ? Whz : (g == 1) ? Whr : Whh;
    int n0 = nt * 64, k0 = kt * 64;
    int tr = threadIdx.x >> 6, tc = threadIdx.x & 63;
    #pragma unroll
    for (int i = 0; i < 16; i++) {
        int kl = i * 4 + tr, k = k0 + kl;
        lds[kl][tc] = (k < 512) ? Wx[(size_t)k * Hh + n0 + tc]
                                : Wh[(size_t)(k - 512) * Hh + n0 + tc];
    }
    __syncthreads();
    #pragma unroll
    for (int i = 0; i < 16; i++) {
        int nl = i * 4 + tr;
        WT[((size_t)g * Hh + n0 + nl) * KK + k0 + tc] = f2b(lds[tc][nl]);
    }
}

__global__ __launch_bounds__(256, 1) void gru_persist(
    const float* __restrict__ inp, const ushort_t* __restrict__ XB, int use_xb,
    const float* __restrict__ bz, const float* __restrict__ br, const float* __restrict__ bh,
    ushort_t* HB, ushort_t* RH, const ushort_t* __restrict__ WT,
    uint32* flags, float* __restrict__ out) {
    __shared__ ushort_t WL[3 * 16 * KP];    // 148224 B, resident all 512 steps
    __shared__ ushort_t stage[4][256];      // per-wave 16x16 bf16 store-coalescing tile

    const int bi = blockIdx.x;
    const int tid = threadIdx.x;

    // prologue: stage [3][16][1536] weight slice into LDS
    for (int r = tid >> 4; r < 48; r += 16) {
        const ushort_t* src = WT + ((size_t)(r >> 4) * Hh + bi * 16 + (r & 15)) * KK;
        ushort_t* dst = WL + (size_t)r * KP;
        for (int c = tid & 15; c < 192; c += 16)
            *reinterpret_cast<uint4*>(dst + c * 8) = *reinterpret_cast<const uint4*>(src + c * 8);
    }

    const int l = tid & 63, w = tid >> 6;
    const int lrow = l & 15, lq = l >> 4;
    const int lk8 = lq << 3;

    const int arow = w * 16 + lrow;                 // A-frag row (batch)
    const int brow0 = w * 16 + lq * 4;              // C/D frag row base (batch)
    const float*    xbF = inp + (size_t)arow * (Tt * Dd) + lk8;
    const ushort_t* xbB = XB + (size_t)arow * (Tt * Dd) + lk8;
    const ushort_t* hbase = HB + arow * Hh + lk8;
    const ushort_t* rbase = RH + arow * Hh + lk8;
    const int ncol = bi * 16 + lrow;
    const ushort_t* wlz = WL + (0 * 16 + lrow) * KP + lk8;
    const ushort_t* wlr = WL + (1 * 16 + lrow) * KP + lk8;
    const ushort_t* wlh = WL + (2 * 16 + lrow) * KP + lk8;
    const float bzv = bz[ncol], brv = br[ncol], bhv = bh[ncol];

    // store-path indices (coalesced 8B per lane of a 16x16 tile)
    const size_t strow = (size_t)(w * 16 + (l >> 2)) * Hh + bi * 16 + (l & 3) * 4;
    ushort_t* stW = &stage[w][0];
    const int stw_off = (l >> 2) * 16 + (l & 3) * 4;

    float hold[4];
    #pragma unroll
    for (int j = 0; j < 4; j++) hold[j] = b2f(HB[(size_t)(brow0 + j) * Hh + ncol]);

    __syncthreads();

    for (int t = 0; t < Tt; ++t) {
        // ---- x frags + x-part MFMAs: overlap flag(2t) propagation ----
        bf16x8 xa[16];
        if (use_xb) {
            const ushort_t* xp = xbB + (size_t)t * Dd;
            #pragma unroll
            for (int i = 0; i < 16; i++) xa[i] = ld_bf8(xp + i * 32);
        } else {
            const float* xp = xbF + (size_t)t * Dd;
            #pragma unroll
            for (int i = 0; i < 16; i++) xa[i] = ld_x8(xp + i * 32);
        }

        f32x4 az0 = {0,0,0,0}, az1 = {0,0,0,0}, ar0 = {0,0,0,0}, ar1 = {0,0,0,0};
        f32x4 ah0 = {0,0,0,0}, ah1 = {0,0,0,0}, ah2 = {0,0,0,0}, ah3 = {0,0,0,0};
        #pragma unroll
        for (int kk = 0; kk < 16; kk += 2) {
            const int o = kk * 32;
            az0 = MFMA(xa[kk],     ld_bf8(wlz + o),      az0);
            az1 = MFMA(xa[kk + 1], ld_bf8(wlz + o + 32), az1);
            ar0 = MFMA(xa[kk],     ld_bf8(wlr + o),      ar0);
            ar1 = MFMA(xa[kk + 1], ld_bf8(wlr + o + 32), ar1);
            ah0 = MFMA(xa[kk],     ld_bf8(wlh + o),      ah0);
            ah1 = MFMA(xa[kk + 1], ld_bf8(wlh + o + 32), ah1);
        }

        b_wait(flags, 2u * (uint32)t);     // HB(t) visible

        // ---- phase A h-part: device-coherent HB loads ----
        #pragma unroll
        for (int kk = 0; kk < 32; kk += 2) {
            const int o = kk * 32;
            bf16x8 a0 = ld_a8(hbase + o);
            bf16x8 a1 = ld_a8(hbase + o + 32);
            az0 = MFMA(a0, ld_bf8(wlz + 512 + o),      az0);
            az1 = MFMA(a1, ld_bf8(wlz + 512 + o + 32), az1);
            ar0 = MFMA(a0, ld_bf8(wlr + 512 + o),      ar0);
            ar1 = MFMA(a1, ld_bf8(wlr + 512 + o + 32), ar1);
        }
        f32x4 az = az0 + az1, ar = ar0 + ar1;
        float zreg[4];
        #pragma unroll
        for (int j = 0; j < 4; j++) {
            float zz = 1.f / (1.f + __expf(-(az[j] + bzv)));
            float rr = 1.f / (1.f + __expf(-(ar[j] + brv)));
            zreg[j] = zz;
            stW[(lq * 4 + j) * 16 + lrow] = f2b(rr * hold[j]);
        }
        asm volatile("s_waitcnt lgkmcnt(0)" ::: "memory");
        st_a8(RH + strow, *reinterpret_cast<const ull*>(stW + stw_off));
        b_arrive(flags, 2u * (uint32)t + 1u);
        b_wait(flags, 2u * (uint32)t + 1u);

        // ---- phase B: (R*H)@W_hh ----
        #pragma unroll
        for (int kk = 0; kk < 32; kk += 4) {
            const int o = kk * 32;
            bf16x8 a0 = ld_a8(rbase + o);
            bf16x8 a1 = ld_a8(rbase + o + 32);
            bf16x8 a2 = ld_a8(rbase + o + 64);
            bf16x8 a3 = ld_a8(rbase + o + 96);
            ah0 = MFMA(a0, ld_bf8(wlh + 512 + o),      ah0);
            ah1 = MFMA(a1, ld_bf8(wlh + 512 + o + 32), ah1);
            ah2 = MFMA(a2, ld_bf8(wlh + 512 + o + 64), ah2);
            ah3 = MFMA(a3, ld_bf8(wlh + 512 + o + 96), ah3);
        }
        f32x4 ah = (ah0 + ah1) + (ah2 + ah3);
        float hn[4];
        #pragma unroll
        for (int j = 0; j < 4; j++) {
            float pre = ah[j] + bhv;
            float e = __expf(-2.f * fabsf(pre));
            float th = (1.f - e) / (1.f + e);
            th = copysignf(th, pre);
            float v = zreg[j] * hold[j] + (1.f - zreg[j]) * th;
            hold[j] = v;
            hn[j] = v;
            stW[(lq * 4 + j) * 16 + lrow] = f2b(v);
        }
        asm volatile("s_waitcnt lgkmcnt(0)" ::: "memory");
        st_a8(HB + strow, *reinterpret_cast<const ull*>(stW + stw_off));
        *reinterpret_cast<float4*>(out + (size_t)ncol * (Tt * Bb) + (size_t)t * Bb + brow0) =
            make_float4(hn[0], hn[1], hn[2], hn[3]);
        if (t == Tt - 1) {
            #pragma unroll
            for (int j = 0; j < 4; j++)
                out[OUT2_OFF + (size_t)(brow0 + j) * Hh + ncol] = hn[j];
        }
        b_arrive(flags, 2u * (uint32)t + 2u);
    }
}

extern "C" void kernel_launch(void* const* d_in, const int* in_sizes, int n_in,
                              void* d_out, int out_size, void* d_ws, size_t ws_size,
                              hipStream_t stream) {
    const float* inp   = (const float*)d_in[0];
    const float* state = (const float*)d_in[1];
    const float* Wxz   = (const float*)d_in[2];
    const float* Whz   = (const float*)d_in[3];
    const float* bz    = (const float*)d_in[4];
    const float* Wxr   = (const float*)d_in[5];
    const float* Whr   = (const float*)d_in[6];
    const float* br    = (const float*)d_in[7];
    const float* Wxh   = (const float*)d_in[8];
    const float* Whh   = (const float*)d_in[9];
    const float* bh    = (const float*)d_in[10];
    float* out = (float*)d_out;

    char* ws = (char*)d_ws;
    ushort_t* HB    = (ushort_t*)(ws);
    ushort_t* RH    = (ushort_t*)(ws + 131072);
    ushort_t* WT    = (ushort_t*)(ws + 262144);
    uint32*   flags = (uint32*)(ws + FLAGS_OFF);
    ushort_t* XB    = (ushort_t*)(ws + XB_OFF);
    int use_xb = (ws_size >= XB_OFF + XB_BYTES) ? 1 : 0;

    k_init<<<dim3(256), dim3(256), 0, stream>>>(state, HB, flags);
    k_wt<<<dim3(1152), dim3(256), 0, stream>>>(Wxz, Whz, Wxr, Whr, Wxh, Whh, WT);
    if (use_xb)
        k_xb<<<dim3(8192), dim3(256), 0, stream>>>(inp, XB);

    void* args[] = {(void*)&inp, (void*)&XB, (void*)&use_xb,
                    (void*)&bz, (void*)&br, (void*)&bh,
                    (void*)&HB, (void*)&RH, (void*)&WT, (void*)&flags, (void*)&out};
    hipError_t e = hipLaunchCooperativeKernel((const void*)gru_persist, dim3(NBLK), dim3(256),
                                              args, 0, stream);
    if (e != hipSuccess) {
        gru_persist<<<dim3(NBLK), dim3(256), 0, stream>>>(inp, XB, use_xb, bz, br, bh,
                                                          HB, RH, WT, flags, out);
    }
}